// Round 8
// baseline (619.081 us; speedup 1.0000x reference)
//
#include <hip/hip_runtime.h>
#include <stdint.h>

// ---- problem constants ----
#define B_N   2
#define HQ_N  32
#define HKV_N 8
#define QL_N  1024
#define SL_N  4096
#define DH_N  128
#define ROPE_N 64
#define RANK_N 512

typedef _Float16 f16;
typedef _Float16 half8 __attribute__((ext_vector_type(8)));
typedef __fp16 fp16x2 __attribute__((ext_vector_type(2)));
typedef float floatx16 __attribute__((ext_vector_type(16)));
typedef int int2v __attribute__((ext_vector_type(2)));

union H8 { half8 h; uint64_t q[2]; };
union PK2 { fp16x2 h; uint32_t u; };
union BFU { uint32_t u[4]; half8 h; };

__device__ inline half8 cvt8(float4 a, float4 b) {
  half8 o;
  o[0] = (f16)a.x; o[1] = (f16)a.y; o[2] = (f16)a.z; o[3] = (f16)a.w;
  o[4] = (f16)b.x; o[5] = (f16)b.y; o[6] = (f16)b.z; o[7] = (f16)b.w;
  return o;
}

// ---------------------------------------------------------------------------
// prep 1 (fused): Krf = f16(Kr)  +  weights (M2T2 rotation, WUKh, WUVT).
// grid = 2496 = 2048 convert + 448 weights.
// ---------------------------------------------------------------------------
__global__ __launch_bounds__(256) void k_prep(const float* __restrict__ Kr,
                                              const float* __restrict__ Ul,
                                              const float* __restrict__ WUK,
                                              const float* __restrict__ WUV,
                                              f16* __restrict__ Krf,
                                              f16* __restrict__ M2T2,
                                              f16* __restrict__ WUKh,
                                              f16* __restrict__ WUVT) {
  int bid = blockIdx.x;
  if (bid < 2048) {
    size_t idx = ((size_t)bid * 256 + threadIdx.x) * 8;  // 4194304 f32
    float4 a = *(const float4*)(Kr + idx);
    float4 b = *(const float4*)(Kr + idx + 4);
    *(half8*)(Krf + idx) = cvt8(a, b);
  } else {
    int idx = (bid - 2048) * 256 + threadIdx.x;   // < 114688
    if (idx < 16384) {
      int c = idx >> 7, d = idx & 127;
      float v = 0.f;
      if (c < 64) { if (d >= 64) v = Ul[c * 64 + (d - 64)]; }
      else        { if (d < 64)  v = Ul[(c - 64) * 64 + d]; }
      M2T2[idx] = (f16)v;
    } else if (idx < 49152) {
      int i = idx - 16384;
      WUKh[i] = (f16)WUK[i];
    } else {
      int i = idx - 49152;             // WUVT[c][r] = WUV[r][c]
      int c = i >> 9, r = i & 511;
      WUVT[i] = (f16)WUV[r * 128 + c];
    }
  }
}

// ---------------------------------------------------------------------------
// prep 2 (fused): Kn[b][s][64] = C@WUK^T  AND  CWT[b][c][s] = (C@WUV)^T.
// grid = 256; chains split across waves; C read as f32 (cvt in reg).
// ---------------------------------------------------------------------------
__global__ __launch_bounds__(256) void k_kncw(const float* __restrict__ C,
                                              const f16* __restrict__ WUKh,
                                              const f16* __restrict__ WUVT,
                                              f16* __restrict__ Kn,
                                              f16* __restrict__ CWT) {
  int t = threadIdx.x;
  int wave = t >> 6, lane = t & 63, l31 = lane & 31, lhi = lane >> 5;
  int b = blockIdx.x >> 7, st = blockIdx.x & 127;
  int s0 = st * 32;
  const float* cp = C + ((size_t)b * SL_N + s0 + l31) * RANK_N + lhi * 8;
  floatx16 a0, a1;
#pragma unroll
  for (int r = 0; r < 16; r++) { a0[r] = 0.f; a1[r] = 0.f; }
  // chains: w0: Kn ct0+ct1 | w1: CWT ct0 | w2: CWT ct1+ct2 | w3: CWT ct3
#pragma unroll 4
  for (int kk = 0; kk < 32; ++kk) {
    float4 fa = *(const float4*)(cp + kk * 16);
    float4 fb = *(const float4*)(cp + kk * 16 + 4);
    half8 cf = cvt8(fa, fb);
    if (wave == 0) {
      half8 b0 = *(const half8*)(WUKh + (size_t)l31 * RANK_N + kk * 16 + lhi * 8);
      half8 b1 = *(const half8*)(WUKh + (size_t)(32 + l31) * RANK_N + kk * 16 + lhi * 8);
      a0 = __builtin_amdgcn_mfma_f32_32x32x16_f16(cf, b0, a0, 0, 0, 0);
      a1 = __builtin_amdgcn_mfma_f32_32x32x16_f16(cf, b1, a1, 0, 0, 0);
    } else if (wave == 1) {
      half8 w0 = *(const half8*)(WUVT + (size_t)l31 * RANK_N + kk * 16 + lhi * 8);
      a0 = __builtin_amdgcn_mfma_f32_32x32x16_f16(w0, cf, a0, 0, 0, 0);
    } else if (wave == 2) {
      half8 w1 = *(const half8*)(WUVT + (size_t)(32 + l31) * RANK_N + kk * 16 + lhi * 8);
      half8 w2 = *(const half8*)(WUVT + (size_t)(64 + l31) * RANK_N + kk * 16 + lhi * 8);
      a0 = __builtin_amdgcn_mfma_f32_32x32x16_f16(w1, cf, a0, 0, 0, 0);
      a1 = __builtin_amdgcn_mfma_f32_32x32x16_f16(w2, cf, a1, 0, 0, 0);
    } else {
      half8 w3 = *(const half8*)(WUVT + (size_t)(96 + l31) * RANK_N + kk * 16 + lhi * 8);
      a0 = __builtin_amdgcn_mfma_f32_32x32x16_f16(w3, cf, a0, 0, 0, 0);
    }
  }
  if (wave == 0) {
#pragma unroll
    for (int r = 0; r < 16; r++) {
      int row = (r & 3) + 8 * (r >> 2) + 4 * lhi;
      Kn[((size_t)b * SL_N + s0 + row) * 64 + l31]      = (f16)a0[r];
      Kn[((size_t)b * SL_N + s0 + row) * 64 + 32 + l31] = (f16)a1[r];
    }
  } else if (wave == 1) {
#pragma unroll
    for (int r = 0; r < 16; r++) {
      int row = (r & 3) + 8 * (r >> 2) + 4 * lhi;
      CWT[((size_t)b * DH_N + row) * SL_N + s0 + l31] = (f16)a0[r];
    }
  } else if (wave == 2) {
#pragma unroll
    for (int r = 0; r < 16; r++) {
      int row = (r & 3) + 8 * (r >> 2) + 4 * lhi;
      CWT[((size_t)b * DH_N + 32 + row) * SL_N + s0 + l31] = (f16)a0[r];
      CWT[((size_t)b * DH_N + 64 + row) * SL_N + s0 + l31] = (f16)a1[r];
    }
  } else {
#pragma unroll
    for (int r = 0; r < 16; r++) {
      int row = (r & 3) + 8 * (r >> 2) + 4 * lhi;
      CWT[((size_t)b * DH_N + 96 + row) * SL_N + s0 + l31] = (f16)a0[r];
    }
  }
}

// ---------------------------------------------------------------------------
// flash kernel, s-split x2: grid 1024 = (half, b, h, qt); each block does
// 32 s-tiles (2048 s) and emits unnormalized Opart + (m,l) per q.
// Single kbuf + single cbuf (LDS 34.3 KB -> 4 blocks/CU = 16 waves/CU).
// Per iter: [S^T; softmax; pack; PV] barrier [commit(t+1); issue(t+2)]
// barrier  -- commit-after-PV preserved, full-iteration load flight.
// THR defer-rescale (base-2 THR=12): P bounded by 4096, merge is exact.
// ---------------------------------------------------------------------------
#define KROW 132   // 264 B stride = 66 dw == 2 mod 32 -> 2-way (free)
#define CROW 68    // 136 B stride; chunk XOR-swizzled

__global__ __launch_bounds__(256, 4) void k_flash(
    const float* __restrict__ Q, const f16* __restrict__ M2T2,
    const f16* __restrict__ Kn, const f16* __restrict__ Krf,
    const f16* __restrict__ CWT, float* __restrict__ Opart,
    float* __restrict__ Ml) {
  __shared__ __align__(16) char smem[34304];
  f16* kbuf = (f16*)smem;                     // [64][132] 16896 B
  f16* cbuf = (f16*)(smem + 16896);           // [128][68] 17408 B
  f16* qs   = (f16*)smem;                     // prologue [128][132] 33792 B
  float* ot = (float*)smem;                   // epilogue [64][133] 34048 B

  int t = threadIdx.x;
  int wave = t >> 6, lane = t & 63, l31 = lane & 31, lhi = lane >> 5;
  int rest = blockIdx.x & 511, half = blockIdx.x >> 9;
  int qt = rest & 7; int h = (rest >> 3) & 31; int b = rest >> 8;
  int kv = h >> 2;
  int qloc = wave * 32 + l31;
  int tb = half * 32;   // tile base (32 tiles of 64 s per half)

  const f16* Knb = Kn + (size_t)b * SL_N * 64;
  const f16* Kb  = Krf + (size_t)(b * HKV_N + kv) * SL_N * ROPE_N;
  const f16* Wb  = CWT + (size_t)b * DH_N * SL_N;

  // staging maps (block-unique, coalesced):
  int kr = t >> 3, kc = t & 7;
  int cA = t >> 2, cch = t & 3;
  const f16* pKn = Knb + (size_t)(tb * 64 + kr) * 64 + kc * 8;
  const f16* pKr = Kb + (size_t)(tb * 64 + kr) * 64 + kc * 8;
  const f16* pW0 = Wb + (size_t)cA * SL_N + tb * 64;
  const f16* pW1 = Wb + (size_t)(64 + cA) * SL_N + tb * 64;
  int sw0 = ((cch) ^ (cA & 7)) * 8;
  int sw1 = ((cch + 4) ^ (cA & 7)) * 8;
  int rsw = l31 & 7;

  // persistent staging registers
  H8 a0, a1, r0, r1, c0v, c1v, c2v, c3v;
  auto issue = [&](int tt) {   // tt = local tile index; may run past end (OOB-safe in ws)
    size_t ko = (size_t)tt * (64 * 64);
    int soff = tt * 64;
    a0.h  = *(const half8*)(pKn + ko);
    a1.h  = *(const half8*)(pKn + ko + 32 * 64);
    r0.h  = *(const half8*)(pKr + ko);
    r1.h  = *(const half8*)(pKr + ko + 32 * 64);
    c0v.h = *(const half8*)(pW0 + soff + cch * 8);
    c1v.h = *(const half8*)(pW0 + soff + (cch + 4) * 8);
    c2v.h = *(const half8*)(pW1 + soff + cch * 8);
    c3v.h = *(const half8*)(pW1 + soff + (cch + 4) * 8);
  };
  auto commit = [&]() {
    uint64_t* d;
    d = (uint64_t*)(kbuf + kr * KROW + kc * 8);             d[0] = a0.q[0]; d[1] = a0.q[1];
    d = (uint64_t*)(kbuf + (kr + 32) * KROW + kc * 8);      d[0] = a1.q[0]; d[1] = a1.q[1];
    d = (uint64_t*)(kbuf + kr * KROW + 64 + kc * 8);        d[0] = r0.q[0]; d[1] = r0.q[1];
    d = (uint64_t*)(kbuf + (kr + 32) * KROW + 64 + kc * 8); d[0] = r1.q[0]; d[1] = r1.q[1];
    d = (uint64_t*)(cbuf + cA * CROW + sw0);                d[0] = c0v.q[0]; d[1] = c0v.q[1];
    d = (uint64_t*)(cbuf + cA * CROW + sw1);                d[0] = c1v.q[0]; d[1] = c1v.q[1];
    d = (uint64_t*)(cbuf + (64 + cA) * CROW + sw0);         d[0] = c2v.q[0]; d[1] = c2v.q[1];
    d = (uint64_t*)(cbuf + (64 + cA) * CROW + sw1);         d[0] = c3v.q[0]; d[1] = c3v.q[1];
  };

  // ---- fused Qeff prologue (tile-0 loads in flight underneath) ----
  issue(0);
  half8 qf[8];
  {
    const float* qp = Q + ((size_t)(b * HQ_N + h) * QL_N + qt * 128 + qloc) * DH_N + lhi * 8;
    floatx16 acc[4];
#pragma unroll
    for (int ct = 0; ct < 4; ct++)
#pragma unroll
      for (int r = 0; r < 16; r++) acc[ct][r] = 0.f;
#pragma unroll
    for (int kk = 0; kk < 8; ++kk) {
      float4 fa = *(const float4*)(qp + kk * 16);
      float4 fb = *(const float4*)(qp + kk * 16 + 4);
      half8 af = cvt8(fa, fb);
#pragma unroll
      for (int ct = 0; ct < 4; ct++) {
        half8 bf = *(const half8*)(M2T2 + (size_t)(ct * 32 + l31) * 128 + kk * 16 + lhi * 8);
        acc[ct] = __builtin_amdgcn_mfma_f32_32x32x16_f16(af, bf, acc[ct], 0, 0, 0);
      }
    }
    const float LOG2E = 1.44269504f;
#pragma unroll
    for (int ct = 0; ct < 4; ct++)
#pragma unroll
      for (int r = 0; r < 16; r++) {
        int row = (r & 3) + 8 * (r >> 2) + 4 * lhi;
        qs[(wave * 32 + row) * 132 + ct * 32 + l31] = (f16)(acc[ct][r] * LOG2E);
      }
  }
  __syncthreads();
#pragma unroll
  for (int kk = 0; kk < 8; kk++)
    qf[kk] = *(const half8*)(qs + (size_t)qloc * 132 + kk * 16 + lhi * 8);
  __syncthreads();   // qs dead; smem -> kbuf/cbuf
  commit();          // tile 0 (loads had the whole prologue to land)
  issue(1);
  __syncthreads();   // tile 0 visible

  floatx16 oacc[4];
#pragma unroll
  for (int ct = 0; ct < 4; ct++)
#pragma unroll
    for (int r = 0; r < 16; r++) oacc[ct][r] = 0.f;
  float m_run = -1e30f, l_run = 0.f;

  for (int it = 0; it < 32; ++it) {
    // ---- S^T = K_eff(A) . Q^T(B), K=128, two 32-s blocks ----
    floatx16 sa0, sa1;
#pragma unroll
    for (int r = 0; r < 16; r++) { sa0[r] = 0.f; sa1[r] = 0.f; }
    {
      const f16* ka0 = kbuf + l31 * KROW + lhi * 8;
      const f16* ka1 = kbuf + (32 + l31) * KROW + lhi * 8;
      __builtin_amdgcn_s_setprio(1);
#pragma unroll
      for (int kk = 0; kk < 8; kk++) {
        H8 x0, x1;
        const uint64_t* p0 = (const uint64_t*)(ka0 + kk * 16);
        const uint64_t* p1 = (const uint64_t*)(ka1 + kk * 16);
        x0.q[0] = p0[0]; x0.q[1] = p0[1];
        x1.q[0] = p1[0]; x1.q[1] = p1[1];
        sa0 = __builtin_amdgcn_mfma_f32_32x32x16_f16(x0.h, qf[kk], sa0, 0, 0, 0);
        sa1 = __builtin_amdgcn_mfma_f32_32x32x16_f16(x1.h, qf[kk], sa1, 0, 0, 0);
      }
      __builtin_amdgcn_s_setprio(0);
    }

    // ---- online softmax, base-2, THR defer-rescale ----
    {
      float u0 = -1e30f, u1 = -1e30f, u2 = -1e30f, u3 = -1e30f;
#pragma unroll
      for (int r = 0; r < 16; r += 4) {
        u0 = fmaxf(u0, fmaxf(sa0[r], sa1[r]));
        u1 = fmaxf(u1, fmaxf(sa0[r + 1], sa1[r + 1]));
        u2 = fmaxf(u2, fmaxf(sa0[r + 2], sa1[r + 2]));
        u3 = fmaxf(u3, fmaxf(sa0[r + 3], sa1[r + 3]));
      }
      float mt = fmaxf(fmaxf(u0, u1), fmaxf(u2, u3));
      mt = fmaxf(mt, __shfl_xor(mt, 32, 64));
      if (__any(mt > m_run + 12.f)) {   // deferred: P bounded by 2^12
        float m_new = fmaxf(m_run, mt);
        float alpha = __builtin_amdgcn_exp2f(m_run - m_new);
        l_run *= alpha;
#pragma unroll
        for (int ct = 0; ct < 4; ct++)
#pragma unroll
          for (int r = 0; r < 16; r++) oacc[ct][r] *= alpha;
        m_run = m_new;
      }
      float p0 = 0.f, p1 = 0.f, p2 = 0.f, p3 = 0.f;
#pragma unroll
      for (int r = 0; r < 16; r += 4) {
        sa0[r] = __builtin_amdgcn_exp2f(sa0[r] - m_run);         p0 += sa0[r];
        sa0[r + 1] = __builtin_amdgcn_exp2f(sa0[r + 1] - m_run); p1 += sa0[r + 1];
        sa0[r + 2] = __builtin_amdgcn_exp2f(sa0[r + 2] - m_run); p2 += sa0[r + 2];
        sa0[r + 3] = __builtin_amdgcn_exp2f(sa0[r + 3] - m_run); p3 += sa0[r + 3];
      }
#pragma unroll
      for (int r = 0; r < 16; r += 4) {
        sa1[r] = __builtin_amdgcn_exp2f(sa1[r] - m_run);         p0 += sa1[r];
        sa1[r + 1] = __builtin_amdgcn_exp2f(sa1[r + 1] - m_run); p1 += sa1[r + 1];
        sa1[r + 2] = __builtin_amdgcn_exp2f(sa1[r + 2] - m_run); p2 += sa1[r + 2];
        sa1[r + 3] = __builtin_amdgcn_exp2f(sa1[r + 3] - m_run); p3 += sa1[r + 3];
      }
      float psum = (p0 + p1) + (p2 + p3);
      psum += __shfl_xor(psum, 32, 64);
      l_run += psum;
    }

    // ---- build 4 PV B-fragments in-register (cvt_pkrtz + permlane32_swap) ----
    half8 bfr0, bfr1, bfr2, bfr3;
    {
      uint32_t pk[8];
#pragma unroll
      for (int g = 0; g < 8; ++g) {
        PK2 pu; pu.h = __builtin_amdgcn_cvt_pkrtz(sa0[2 * g], sa0[2 * g + 1]);
        pk[g] = pu.u;
      }
      int2v v0 = __builtin_amdgcn_permlane32_swap((int)pk[0], (int)pk[2], false, false);
      pk[0] = (uint32_t)v0.x; pk[2] = (uint32_t)v0.y;
      int2v v1 = __builtin_amdgcn_permlane32_swap((int)pk[1], (int)pk[3], false, false);
      pk[1] = (uint32_t)v1.x; pk[3] = (uint32_t)v1.y;
      int2v v2 = __builtin_amdgcn_permlane32_swap((int)pk[4], (int)pk[6], false, false);
      pk[4] = (uint32_t)v2.x; pk[6] = (uint32_t)v2.y;
      int2v v3 = __builtin_amdgcn_permlane32_swap((int)pk[5], (int)pk[7], false, false);
      pk[5] = (uint32_t)v3.x; pk[7] = (uint32_t)v3.y;
      BFU f0, f1;
      f0.u[0] = pk[0]; f0.u[1] = pk[1]; f0.u[2] = pk[2]; f0.u[3] = pk[3];
      f1.u[0] = pk[4]; f1.u[1] = pk[5]; f1.u[2] = pk[6]; f1.u[3] = pk[7];
      bfr0 = f0.h; bfr1 = f1.h;
    }
    {
      uint32_t pk[8];
#pragma unroll
      for (int g = 0; g < 8; ++g) {
        PK2 pu; pu.h = __builtin_amdgcn_cvt_pkrtz(sa1[2 * g], sa1[2 * g + 1]);
        pk[g] = pu.u;
      }
      int2v v0 = __builtin_amdgcn_permlane32_swap((int)pk[0], (int)pk[2], false, false);
      pk[0] = (uint32_t)v0.x; pk[2] = (uint32_t)v0.y;
      int2v v1 = __builtin_amdgcn_permlane32_swap((int)pk[1], (int)pk[3], false, false);
      pk[1] = (uint32_t)v1.x; pk[3] = (uint32_t)v1.y;
      int2v v2 = __builtin_amdgcn_permlane32_swap((int)pk[4], (int)pk[6], false, false);
      pk[4] = (uint32_t)v2.x; pk[6] = (uint32_t)v2.y;
      int2v v3 = __builtin_amdgcn_permlane32_swap((int)pk[5], (int)pk[7], false, false);
      pk[5] = (uint32_t)v3.x; pk[7] = (uint32_t)v3.y;
      BFU f0, f1;
      f0.u[0] = pk[0]; f0.u[1] = pk[1]; f0.u[2] = pk[2]; f0.u[3] = pk[3];
      f1.u[0] = pk[4]; f1.u[1] = pk[5]; f1.u[2] = pk[6]; f1.u[3] = pk[7];
      bfr2 = f0.h; bfr3 = f1.h;
    }

    // ---- PV: out^T = CW^T(A) . P^T(B), 4 ksteps (swizzled cbuf reads) ----
    __builtin_amdgcn_s_setprio(1);
#pragma unroll
    for (int ks = 0; ks < 4; ++ks) {
      half8 bfh = (ks == 0) ? bfr0 : (ks == 1) ? bfr1 : (ks == 2) ? bfr2 : bfr3;
#pragma unroll
      for (int ct = 0; ct < 4; ct++) {
        H8 af;
        const uint64_t* pa = (const uint64_t*)(cbuf + (ct * 32 + l31) * CROW +
                                               (((ks * 2 + lhi) ^ rsw) * 8));
        af.q[0] = pa[0]; af.q[1] = pa[1];
        oacc[ct] = __builtin_amdgcn_mfma_f32_32x32x16_f16(af.h, bfh, oacc[ct], 0, 0, 0);
      }
    }
    __builtin_amdgcn_s_setprio(0);

    __syncthreads();   // all reads of kbuf/cbuf done
    commit();          // tile it+1 (loads had a full iteration of flight)
    issue(it + 2);     // regs free; full-iteration flight for tile it+2
    __syncthreads();   // commits visible
  }

  // ---- epilogue: Opart (unnormalized) + Ml ----
  float* opb = Opart + (size_t)blockIdx.x * (128 * 128);
#pragma unroll
  for (int p = 0; p < 2; ++p) {
    __syncthreads();
    if ((qloc >> 6) == p) {
      int lr = qloc & 63;
#pragma unroll
      for (int ct = 0; ct < 4; ct++)
#pragma unroll
        for (int r = 0; r < 16; r++) {
          int c = ct * 32 + (r & 3) + 8 * (r >> 2) + 4 * lhi;
          ot[lr * 133 + c] = oacc[ct][r];
        }
    }
    __syncthreads();
#pragma unroll
    for (int i = 0; i < 8; i++) {
      int flat = i * 256 + t; int q = flat >> 5, ch = flat & 31;
      float4 v;
      v.x = ot[q * 133 + ch * 4 + 0];
      v.y = ot[q * 133 + ch * 4 + 1];
      v.z = ot[q * 133 + ch * 4 + 2];
      v.w = ot[q * 133 + ch * 4 + 3];
      *(float4*)(opb + (size_t)(p * 64 + q) * 128 + ch * 4) = v;
    }
  }
  if (lane < 32) {
    float* mlb = Ml + (size_t)blockIdx.x * 256;
    mlb[qloc * 2]     = m_run;
    mlb[qloc * 2 + 1] = l_run;
  }
}

// ---------------------------------------------------------------------------
// merge: out = (O0*2^(m0-m) + O1*2^(m1-m)) / (l0*2^(m0-m)+l1*2^(m1-m)).
// grid = 512 (b,h,qt); fully-coalesced float4 streams.
// ---------------------------------------------------------------------------
__global__ __launch_bounds__(256) void k_merge(const float* __restrict__ Opart,
                                               const float* __restrict__ Ml,
                                               float* __restrict__ out) {
  __shared__ float sm[512];
  int rest = blockIdx.x;
  int t = threadIdx.x;
  sm[t] = Ml[(size_t)rest * 256 + t];                 // half 0: [128][2]
  sm[256 + t] = Ml[(size_t)(512 + rest) * 256 + t];   // half 1
  __syncthreads();
  int qt = rest & 7; int h = (rest >> 3) & 31; int b = rest >> 8;
  const float* O0 = Opart + (size_t)rest * 16384;
  const float* O1 = Opart + (size_t)(512 + rest) * 16384;
  float* dst = out + ((size_t)(b * HQ_N + h) * QL_N + qt * 128) * DH_N;
#pragma unroll
  for (int i = 0; i < 16; i++) {
    int flat = i * 1024 + t * 4;
    int q = flat >> 7;
    float m0 = sm[q * 2], l0 = sm[q * 2 + 1];
    float m1 = sm[256 + q * 2], l1 = sm[256 + q * 2 + 1];
    float m = fmaxf(m0, m1);
    float a0 = exp2f(m0 - m), a1 = exp2f(m1 - m);
    float inv = 1.f / (l0 * a0 + l1 * a1);
    a0 *= inv; a1 *= inv;
    float4 v0 = *(const float4*)(O0 + flat);
    float4 v1 = *(const float4*)(O1 + flat);
    float4 o;
    o.x = v0.x * a0 + v1.x * a1;
    o.y = v0.y * a0 + v1.y * a1;
    o.z = v0.z * a0 + v1.z * a1;
    o.w = v0.w * a0 + v1.w * a1;
    *(float4*)(dst + flat) = o;
  }
}

// ---------------------------------------------------------------------------
extern "C" void kernel_launch(void* const* d_in, const int* in_sizes, int n_in,
                              void* d_out, int out_size, void* d_ws, size_t ws_size,
                              hipStream_t stream) {
  (void)in_sizes; (void)n_in; (void)out_size; (void)ws_size;
  const float* Q   = (const float*)d_in[0];
  const float* C   = (const float*)d_in[1];
  const float* Kr  = (const float*)d_in[2];
  const float* Ul  = (const float*)d_in[3];
  const float* WUK = (const float*)d_in[4];
  const float* WUV = (const float*)d_in[5];
  float* out = (float*)d_out;
  char* ws = (char*)d_ws;
  // workspace carve (~80 MB); every flash-read array has a mapped successor
  // (OOB-slack for the guard-free final issue/commit).
  f16* Krf    = (f16*)ws;                    //  8,388,608 B
  f16* CWT    = (f16*)(ws + 8388608);        //  2,097,152 B
  f16* Kn     = (f16*)(ws + 10485760);       //  1,048,576 B
  f16* M2T2   = (f16*)(ws + 11534336);       //     32,768 B
  f16* WUKh   = (f16*)(ws + 11567104);       //     65,536 B
  f16* WUVT   = (f16*)(ws + 11632640);       //    131,072 B
  float* Opart= (float*)(ws + 11763712);     // 67,108,864 B
  float* Ml   = (float*)(ws + 78872576);     //  1,048,576 B

  hipLaunchKernelGGL(k_prep,  dim3(2496), dim3(256), 0, stream, Kr, Ul, WUK, WUV, Krf, M2T2, WUKh, WUVT);
  hipLaunchKernelGGL(k_kncw,  dim3(256),  dim3(256), 0, stream, C, WUKh, WUVT, Kn, CWT);
  hipLaunchKernelGGL(k_flash, dim3(1024), dim3(256), 0, stream, Q, M2T2, Kn, Krf, CWT, Opart, Ml);
  hipLaunchKernelGGL(k_merge, dim3(512),  dim3(256), 0, stream, Opart, Ml, out);
}